// Round 2
// baseline (2031.499 us; speedup 1.0000x reference)
//
#include <hip/hip_runtime.h>
#include <math.h>

#define BB 2
#define LL 2048
#define DD 768
#define NH 12
#define HD 64
#define QR 8           // query rows per attention block

// ---------------------------------------------------------------------------
// GEMM: C[M=4096][N=768] = X @ W + bias
// MODE 0: plain row-major store  out[row*DD + col]
// MODE 1: head-major store       out[((b*NH + h)*LL + l)*HD + d]
// ---------------------------------------------------------------------------
template<int MODE>
__global__ __launch_bounds__(256) void gemm_proj(const float* __restrict__ X,
                                                 const float* __restrict__ W,
                                                 const float* __restrict__ bias,
                                                 float* __restrict__ out)
{
    __shared__ float As[16][64];   // As[k][m]
    __shared__ float Bs[16][64];   // Bs[k][n]
    const int tid = threadIdx.x;
    const int m0 = blockIdx.y * 64;
    const int n0 = blockIdx.x * 64;
    const int tm = (tid >> 4) * 4;   // 0..60 step 4
    const int tn = (tid & 15) * 4;

    float acc[4][4] = {};

    for (int k0 = 0; k0 < DD; k0 += 16) {
        // load A tile 64 rows x 16 k (transpose into As[k][m])
        #pragma unroll
        for (int i = 0; i < 4; ++i) {
            int idx = tid + i * 256;          // 0..1023
            int m = idx >> 4, k = idx & 15;
            As[k][m] = X[(size_t)(m0 + m) * DD + (k0 + k)];
        }
        // load B tile 16 k x 64 n
        #pragma unroll
        for (int i = 0; i < 4; ++i) {
            int idx = tid + i * 256;
            int k = idx >> 6, n = idx & 63;
            Bs[k][n] = W[(size_t)(k0 + k) * DD + (n0 + n)];
        }
        __syncthreads();
        #pragma unroll
        for (int k = 0; k < 16; ++k) {
            float4 av = *reinterpret_cast<const float4*>(&As[k][tm]);
            float4 bv = *reinterpret_cast<const float4*>(&Bs[k][tn]);
            float a[4] = {av.x, av.y, av.z, av.w};
            float b[4] = {bv.x, bv.y, bv.z, bv.w};
            #pragma unroll
            for (int i = 0; i < 4; ++i)
                #pragma unroll
                for (int j = 0; j < 4; ++j)
                    acc[i][j] += a[i] * b[j];
        }
        __syncthreads();
    }

    #pragma unroll
    for (int i = 0; i < 4; ++i) {
        int row = m0 + tm + i;
        int b = row >> 11;          // row / LL  (LL = 2048)
        int l = row & (LL - 1);
        #pragma unroll
        for (int j = 0; j < 4; ++j) {
            int col = n0 + tn + j;
            float v = acc[i][j] + bias[col];
            if (MODE == 0) {
                out[(size_t)row * DD + col] = v;
            } else {
                int h = col >> 6, d = col & 63;
                out[(((size_t)(b * NH + h)) * LL + l) * HD + d] = v;
            }
        }
    }
}

// ---------------------------------------------------------------------------
// Attention: per (b,h), per 8-query-row block.
// Full 2048-element score rows in LDS -> exact softmax -> PV.
// ---------------------------------------------------------------------------
__global__ __launch_bounds__(256) void attn_kernel(const float* __restrict__ Qp,
                                                   const float* __restrict__ Kp,
                                                   const float* __restrict__ Vp,
                                                   const float* __restrict__ mask,
                                                   float* __restrict__ Oc)
{
    __shared__ float sc[QR][LL];      // 64 KB
    __shared__ float qs[QR][HD];      // 2 KB
    __shared__ float red[16];

    const int tid = threadIdx.x;
    const int lane = tid & 63;
    const int wv = tid >> 6;          // 4 waves
    const int bh = blockIdx.y;        // 0..23
    const int b  = bh / NH;
    const int h  = bh % NH;
    const int r0 = blockIdx.x * QR;

    const float* Kbase = Kp + (size_t)bh * LL * HD;
    const float* Vbase = Vp + (size_t)bh * LL * HD;
    const float* Qbase = Qp + ((size_t)bh * LL + r0) * HD;

    // stage the 8 query rows (layout in Qp is already [rows][64] contiguous)
    for (int idx = tid; idx < QR * HD; idx += 256)
        qs[idx >> 6][idx & 63] = Qbase[idx];
    __syncthreads();

    // ---- scores: each thread owns 8 key columns (j = tid + 256*t) ----
    for (int j = tid; j < LL; j += 256) {
        const float* Krow = Kbase + (size_t)j * HD;
        float kreg[HD];
        #pragma unroll
        for (int kk = 0; kk < HD / 4; ++kk) {
            float4 t = reinterpret_cast<const float4*>(Krow)[kk];
            kreg[4 * kk + 0] = t.x; kreg[4 * kk + 1] = t.y;
            kreg[4 * kk + 2] = t.z; kreg[4 * kk + 3] = t.w;
        }
        float mterm = (1.0f - mask[(size_t)b * LL + j]) * -99999.0f;
        #pragma unroll
        for (int r = 0; r < QR; ++r) {
            float s = 0.0f;
            #pragma unroll
            for (int kk = 0; kk < HD; ++kk) s += qs[r][kk] * kreg[kk];
            sc[r][j] = s * 0.125f + mterm;   // 1/sqrt(64) = 0.125
        }
    }
    __syncthreads();

    // ---- softmax (exact, row at a time) ----
    for (int r = 0; r < QR; ++r) {
        float mx = -1e30f;
        for (int j = tid; j < LL; j += 256) mx = fmaxf(mx, sc[r][j]);
        #pragma unroll
        for (int o = 32; o > 0; o >>= 1) mx = fmaxf(mx, __shfl_xor(mx, o));
        if (lane == 0) red[wv] = mx;
        __syncthreads();
        mx = fmaxf(fmaxf(red[0], red[1]), fmaxf(red[2], red[3]));

        float sum = 0.0f;
        for (int j = tid; j < LL; j += 256) {
            float e = __expf(sc[r][j] - mx);
            sc[r][j] = e;
            sum += e;
        }
        #pragma unroll
        for (int o = 32; o > 0; o >>= 1) sum += __shfl_xor(sum, o);
        if (lane == 0) red[4 + wv] = sum;
        __syncthreads();
        float inv = 1.0f / (red[4] + red[5] + red[6] + red[7]);
        for (int j = tid; j < LL; j += 256) sc[r][j] *= inv;
        __syncthreads();
    }

    // ---- PV: thread owns output dim d for all 8 rows over a 512-key slice ----
    const int d = tid & 63;
    const int g = tid >> 6;           // 4 key-range groups
    float acc[QR] = {};
    const int j0 = g * (LL / 4), j1 = j0 + (LL / 4);
    for (int j = j0; j < j1; ++j) {
        float vv = Vbase[(size_t)j * HD + d];
        #pragma unroll
        for (int r = 0; r < QR; ++r) acc[r] += sc[r][j] * vv;
    }
    __syncthreads();                   // all reads of sc done
    float* part = &sc[0][0];           // reuse LDS: [4 groups][QR][64]
    #pragma unroll
    for (int r = 0; r < QR; ++r)
        part[((g * QR) + r) * 64 + d] = acc[r];
    __syncthreads();

    for (int idx = tid; idx < QR * 64; idx += 256) {
        int r = idx >> 6, dd = idx & 63;
        float s = part[((0 * QR) + r) * 64 + dd]
                + part[((1 * QR) + r) * 64 + dd]
                + part[((2 * QR) + r) * 64 + dd]
                + part[((3 * QR) + r) * 64 + dd];
        int row = b * LL + (r0 + r);
        int col = h * HD + dd;
        Oc[(size_t)row * DD + col] = s;
    }
}

// ---------------------------------------------------------------------------
extern "C" void kernel_launch(void* const* d_in, const int* in_sizes, int n_in,
                              void* d_out, int out_size, void* d_ws, size_t ws_size,
                              hipStream_t stream)
{
    const float* q    = (const float*)d_in[0];
    const float* k    = (const float*)d_in[1];
    const float* v    = (const float*)d_in[2];
    const float* amask= (const float*)d_in[3];
    const float* Wq   = (const float*)d_in[4];
    const float* bq   = (const float*)d_in[5];
    const float* Wk   = (const float*)d_in[6];
    const float* bk   = (const float*)d_in[7];
    const float* Wv   = (const float*)d_in[8];
    const float* bv   = (const float*)d_in[9];
    const float* Wo   = (const float*)d_in[10];
    const float* bo   = (const float*)d_in[11];
    float* out = (float*)d_out;

    const size_t NPH = (size_t)BB * NH * LL * HD;   // 3,145,728 floats
    float* ws = (float*)d_ws;
    float* Qp = ws;
    float* Kp = ws + NPH;
    float* Vp = ws + 2 * NPH;
    float* Oc = ws + 3 * NPH;

    dim3 ggrid(DD / 64, (BB * LL) / 64);   // (12, 64)
    gemm_proj<1><<<ggrid, 256, 0, stream>>>(q, Wq, bq, Qp);
    gemm_proj<1><<<ggrid, 256, 0, stream>>>(k, Wk, bk, Kp);
    gemm_proj<1><<<ggrid, 256, 0, stream>>>(v, Wv, bv, Vp);

    dim3 agrid(LL / QR, BB * NH);          // (256, 24)
    attn_kernel<<<agrid, 256, 0, stream>>>(Qp, Kp, Vp, amask, Oc);

    gemm_proj<0><<<ggrid, 256, 0, stream>>>(Oc, Wo, bo, out);
}

// Round 4
// 656.793 us; speedup vs baseline: 3.0931x; 3.0931x over previous
//
#include <hip/hip_runtime.h>
#include <math.h>

#define BB 2
#define LL 2048
#define DD 768
#define NH 12
#define HD 64
#define QT 64        // q rows per attention block (4 waves x 16 rows)
#define KT 32        // keys per tile
#define NTILES (LL/KT)

typedef __attribute__((ext_vector_type(8))) short short8;   // 8 bf16
typedef __attribute__((ext_vector_type(4))) float f32x4;

union U8 { unsigned short u[8]; short8 v; };

#define MFMA(a,b,c) __builtin_amdgcn_mfma_f32_16x16x32_bf16((a),(b),(c),0,0,0)

__device__ inline unsigned short f2bf(float x) {          // RNE f32 -> bf16 bits
    unsigned int u = __float_as_uint(x);
    unsigned int r = (u + 0x7fffu + ((u >> 16) & 1u)) >> 16;
    return (unsigned short)r;
}
__device__ inline float bf2f(unsigned short s) {
    return __uint_as_float(((unsigned int)s) << 16);
}
__device__ inline void split2(float x, unsigned short& h, unsigned short& l) {
    h = f2bf(x);
    l = f2bf(x - bf2f(h));
}
// row-XOR swizzle for 128B LDS rows: spreads both transpose-writes and frag-reads
__device__ inline int swz(int row) { return (((row & 7) ^ ((row >> 3) & 7)) << 4); }

// ---------------------------------------------------------------------------
// GEMM: C[M=4096][N=768] = X @ W + bias   (unchanged fp32 baseline)
// MODE 0: row-major store; MODE 1: head-major store [b,h,l,d]
// ---------------------------------------------------------------------------
template<int MODE>
__global__ __launch_bounds__(256) void gemm_proj(const float* __restrict__ X,
                                                 const float* __restrict__ W,
                                                 const float* __restrict__ bias,
                                                 float* __restrict__ out)
{
    __shared__ float As[16][64];
    __shared__ float Bs[16][64];
    const int tid = threadIdx.x;
    const int m0 = blockIdx.y * 64;
    const int n0 = blockIdx.x * 64;
    const int tm = (tid >> 4) * 4;
    const int tn = (tid & 15) * 4;

    float acc[4][4] = {};

    for (int k0 = 0; k0 < DD; k0 += 16) {
        #pragma unroll
        for (int i = 0; i < 4; ++i) {
            int idx = tid + i * 256;
            int m = idx >> 4, k = idx & 15;
            As[k][m] = X[(size_t)(m0 + m) * DD + (k0 + k)];
        }
        #pragma unroll
        for (int i = 0; i < 4; ++i) {
            int idx = tid + i * 256;
            int k = idx >> 6, n = idx & 63;
            Bs[k][n] = W[(size_t)(k0 + k) * DD + (n0 + n)];
        }
        __syncthreads();
        #pragma unroll
        for (int k = 0; k < 16; ++k) {
            float4 av = *reinterpret_cast<const float4*>(&As[k][tm]);
            float4 bv = *reinterpret_cast<const float4*>(&Bs[k][tn]);
            float a[4] = {av.x, av.y, av.z, av.w};
            float b[4] = {bv.x, bv.y, bv.z, bv.w};
            #pragma unroll
            for (int i = 0; i < 4; ++i)
                #pragma unroll
                for (int j = 0; j < 4; ++j)
                    acc[i][j] += a[i] * b[j];
        }
        __syncthreads();
    }

    #pragma unroll
    for (int i = 0; i < 4; ++i) {
        int row = m0 + tm + i;
        int b = row >> 11;
        int l = row & (LL - 1);
        #pragma unroll
        for (int j = 0; j < 4; ++j) {
            int col = n0 + tn + j;
            float v = acc[i][j] + bias[col];
            if (MODE == 0) {
                out[(size_t)row * DD + col] = v;
            } else {
                int h = col >> 6, d = col & 63;
                out[(((size_t)(b * NH + h)) * LL + l) * HD + d] = v;
            }
        }
    }
}

// ---------------------------------------------------------------------------
// Flash attention with bf16x3 (split hi/lo) MFMA — fp32-class accuracy.
// Block: 256 threads = 4 waves; wave owns 16 q-rows; loops 64 key-tiles of 32.
// ---------------------------------------------------------------------------
__global__ __launch_bounds__(256) void attn_mfma(const float* __restrict__ Qp,
                                                 const float* __restrict__ Kp,
                                                 const float* __restrict__ Vp,
                                                 const float* __restrict__ mask,
                                                 float* __restrict__ Oc)
{
    // all LDS rows are 64 ushort = 128B, XOR-swizzled via swz(row)
    __shared__ unsigned short Kh[32 * 64];   // K hi  [key][d]
    __shared__ unsigned short Kl[32 * 64];   // K lo  [key][d]
    __shared__ unsigned short Vt[64 * 64];   // V^T   [d][key_hi(32)|key_lo(32)]
    __shared__ unsigned short Pb[4 * 16 * 64]; // per-wave P [row][key_hi|key_lo]
    __shared__ float mterm[KT];

    const int tid = threadIdx.x;
    const int l   = tid & 63;
    const int w   = tid >> 6;
    const int g   = l >> 4;       // 16-lane group id (0..3)
    const int c   = l & 15;       // position within group
    const int bh  = blockIdx.y;   // 0..23
    const int b   = bh / NH;
    const int h   = bh % NH;
    const int r0  = blockIdx.x * QT;

    // ---- Q fragments (x 1/8 scale folded in), split hi/lo, 2 k-halves ----
    // A-frag: lane holds row = c, d = 32*half + 8*g + j
    short8 qh[2], ql[2];
    {
        const float* qr = Qp + ((size_t)bh * LL + r0 + w * 16 + c) * HD + 8 * g;
        #pragma unroll
        for (int hf = 0; hf < 2; ++hf) {
            U8 ph, pl;
            #pragma unroll
            for (int j = 0; j < 8; ++j) {
                float x = qr[32 * hf + j] * 0.125f;
                split2(x, ph.u[j], pl.u[j]);
            }
            qh[hf] = ph.v; ql[hf] = pl.v;
        }
    }

    f32x4 Oa[4] = {{0,0,0,0},{0,0,0,0},{0,0,0,0},{0,0,0,0}};
    float mrun[4] = {-1e30f,-1e30f,-1e30f,-1e30f};
    float lrun[4] = {0.f,0.f,0.f,0.f};

    const float* Kgb = Kp + (size_t)bh * LL * HD;
    const float* Vgb = Vp + (size_t)bh * LL * HD;

    const int skey = tid >> 3;        // staging: key 0..31
    const int sd0  = (tid & 7) * 8;   // staging: d group

    for (int kt = 0; kt < NTILES; ++kt) {
        __syncthreads();              // previous tile fully consumed
        // ---- stage K tile (hi/lo), [key][d], b128 writes ----
        {
            const float* kg = Kgb + (size_t)(kt * KT + skey) * HD + sd0;
            U8 hh, lo;
            #pragma unroll
            for (int j = 0; j < 8; ++j) split2(kg[j], hh.u[j], lo.u[j]);
            int idx = skey * 64 + (((sd0 * 2) ^ swz(skey)) >> 1);
            *(short8*)&Kh[idx] = hh.v;
            *(short8*)&Kl[idx] = lo.v;
        }
        // ---- stage V tile transposed: Vt[d][key] hi at +0, lo at +64B ----
        {
            const float* vg = Vgb + (size_t)(kt * KT + skey) * HD + sd0;
            #pragma unroll
            for (int j = 0; j < 8; ++j) {
                unsigned short h_, l_;
                split2(vg[j], h_, l_);
                int d = sd0 + j;
                int s = swz(d);
                Vt[d * 64 + (((2 * skey) ^ s) >> 1)]      = h_;
                Vt[d * 64 + (((64 + 2 * skey) ^ s) >> 1)] = l_;
            }
        }
        if (tid < KT)
            mterm[tid] = (1.0f - mask[(size_t)b * LL + kt * KT + tid]) * -99999.0f;
        __syncthreads();

        // ---- scores: S[16 rows][32 keys] as two 16x16 MFMA tiles, bf16x3 ----
        f32x4 s[2];
        #pragma unroll
        for (int th = 0; th < 2; ++th) {
            int row = th * 16 + c;     // B-frag: col = key = row of Ks
            int sw = swz(row);
            const short8 kh0 = *(const short8*)&Kh[row * 64 + (((16 * g     ) ^ sw) >> 1)];
            const short8 kh1 = *(const short8*)&Kh[row * 64 + (((16 * g + 64) ^ sw) >> 1)];
            const short8 kl0 = *(const short8*)&Kl[row * 64 + (((16 * g     ) ^ sw) >> 1)];
            const short8 kl1 = *(const short8*)&Kl[row * 64 + (((16 * g + 64) ^ sw) >> 1)];
            f32x4 a = {0,0,0,0};
            a = MFMA(qh[0], kh0, a); a = MFMA(qh[1], kh1, a);   // hi*hi
            a = MFMA(ql[0], kh0, a); a = MFMA(ql[1], kh1, a);   // lo*hi
            a = MFMA(qh[0], kl0, a); a = MFMA(qh[1], kl1, a);   // hi*lo
            float mt = mterm[th * 16 + c];
            a[0] += mt; a[1] += mt; a[2] += mt; a[3] += mt;
            s[th] = a;
        }

        // ---- online softmax (rows = 4*g + r, reduce across 16-lane group) ----
        float pexp[2][4];
        #pragma unroll
        for (int r = 0; r < 4; ++r) {
            float tm = fmaxf(s[0][r], s[1][r]);
            #pragma unroll
            for (int o = 1; o < 16; o <<= 1) tm = fmaxf(tm, __shfl_xor(tm, o));
            float mn = fmaxf(mrun[r], tm);
            float scale = __expf(mrun[r] - mn);
            float p0 = __expf(s[0][r] - mn);
            float p1 = __expf(s[1][r] - mn);
            float rs = p0 + p1;
            #pragma unroll
            for (int o = 1; o < 16; o <<= 1) rs += __shfl_xor(rs, o);
            lrun[r] = lrun[r] * scale + rs;
            mrun[r] = mn;
            pexp[0][r] = p0; pexp[1][r] = p1;
            #pragma unroll
            for (int n = 0; n < 4; ++n) Oa[n][r] *= scale;
        }

        // ---- P -> per-wave LDS (hi/lo), then read back as A-frags ----
        unsigned short* Pw = &Pb[w * 16 * 64];
        #pragma unroll
        for (int th = 0; th < 2; ++th)
            #pragma unroll
            for (int r = 0; r < 4; ++r) {
                int row = 4 * g + r;
                int sw2 = swz(row);
                unsigned short h_, l_;
                split2(pexp[th][r], h_, l_);
                int keyb = 2 * (th * 16 + c);
                Pw[row * 64 + ((keyb ^ sw2) >> 1)]        = h_;
                Pw[row * 64 + (((64 + keyb) ^ sw2) >> 1)] = l_;
            }
        asm volatile("s_waitcnt lgkmcnt(0)" ::: "memory");  // wave-local WAR safety

        // ---- PV: O[16][64] += P * V  (bf16x3) ----
        {
            int sw2 = swz(c);
            const short8 pa_h = *(const short8*)&Pw[c * 64 + (((16 * g     ) ^ sw2) >> 1)];
            const short8 pa_l = *(const short8*)&Pw[c * 64 + (((64 + 16 * g) ^ sw2) >> 1)];
            #pragma unroll
            for (int n = 0; n < 4; ++n) {
                int vrow = 16 * n + c;
                int sv = swz(vrow);
                const short8 vh = *(const short8*)&Vt[vrow * 64 + (((16 * g     ) ^ sv) >> 1)];
                const short8 vl = *(const short8*)&Vt[vrow * 64 + (((64 + 16 * g) ^ sv) >> 1)];
                Oa[n] = MFMA(pa_h, vh, Oa[n]);
                Oa[n] = MFMA(pa_h, vl, Oa[n]);
                Oa[n] = MFMA(pa_l, vh, Oa[n]);
            }
        }
    }

    // ---- epilogue: O / l, store fp32 row-major [4096][768] ----
    #pragma unroll
    for (int r = 0; r < 4; ++r) {
        float inv = 1.0f / lrun[r];
        int row = r0 + w * 16 + 4 * g + r;
        float* orow = Oc + ((size_t)b * LL + row) * DD + h * HD;
        #pragma unroll
        for (int n = 0; n < 4; ++n)
            orow[16 * n + c] = Oa[n][r] * inv;
    }
}

// ---------------------------------------------------------------------------
extern "C" void kernel_launch(void* const* d_in, const int* in_sizes, int n_in,
                              void* d_out, int out_size, void* d_ws, size_t ws_size,
                              hipStream_t stream)
{
    const float* q    = (const float*)d_in[0];
    const float* k    = (const float*)d_in[1];
    const float* v    = (const float*)d_in[2];
    const float* amask= (const float*)d_in[3];
    const float* Wq   = (const float*)d_in[4];
    const float* bq   = (const float*)d_in[5];
    const float* Wk   = (const float*)d_in[6];
    const float* bk   = (const float*)d_in[7];
    const float* Wv   = (const float*)d_in[8];
    const float* bv   = (const float*)d_in[9];
    const float* Wo   = (const float*)d_in[10];
    const float* bo   = (const float*)d_in[11];
    float* out = (float*)d_out;

    const size_t NPH = (size_t)BB * NH * LL * HD;
    float* ws = (float*)d_ws;
    float* Qp = ws;
    float* Kp = ws + NPH;
    float* Vp = ws + 2 * NPH;
    float* Oc = ws + 3 * NPH;

    dim3 ggrid(DD / 64, (BB * LL) / 64);
    gemm_proj<1><<<ggrid, 256, 0, stream>>>(q, Wq, bq, Qp);
    gemm_proj<1><<<ggrid, 256, 0, stream>>>(k, Wk, bk, Kp);
    gemm_proj<1><<<ggrid, 256, 0, stream>>>(v, Wv, bv, Vp);

    dim3 agrid(LL / QT, BB * NH);          // (32, 24)
    attn_mfma<<<agrid, 256, 0, stream>>>(Qp, Kp, Vp, amask, Oc);

    gemm_proj<0><<<ggrid, 256, 0, stream>>>(Oc, Wo, bo, out);
}

// Round 6
// 410.690 us; speedup vs baseline: 4.9465x; 1.5992x over previous
//
#include <hip/hip_runtime.h>
#include <math.h>

#define BB 2
#define LL 2048
#define DD 768
#define NH 12
#define HD 64
#define QT 64        // q rows per attention block (4 waves x 16 rows)
#define KT 32        // keys per tile
#define NTILES (LL/KT)
#define EL (4096*768)     // elements of one [4096][768] plane
#define WEL (768*768)     // elements of one weight plane

typedef __attribute__((ext_vector_type(8))) short short8;   // 8 bf16
typedef __attribute__((ext_vector_type(4))) float f32x4;
typedef unsigned short ushortT;

union U8 { unsigned short u[8]; short8 v; };

#define MFMA(a,b,c) __builtin_amdgcn_mfma_f32_16x16x32_bf16((a),(b),(c),0,0,0)

__device__ inline unsigned short f2bf(float x) {          // RNE f32 -> bf16 bits
    unsigned int u = __float_as_uint(x);
    unsigned int r = (u + 0x7fffu + ((u >> 16) & 1u)) >> 16;
    return (unsigned short)r;
}
__device__ inline float bf2f(unsigned short s) {
    return __uint_as_float(((unsigned int)s) << 16);
}
__device__ inline void split2(float x, unsigned short& h, unsigned short& l) {
    h = f2bf(x);
    l = f2bf(x - bf2f(h));
}
__device__ inline int swz(int row) { return (((row & 7) ^ ((row >> 3) & 7)) << 4); }

__device__ inline void gl2lds16(const void* g, void* l) {
    __builtin_amdgcn_global_load_lds((__attribute__((address_space(1))) const void*)g,
                                     (__attribute__((address_space(3))) void*)l, 16, 0, 0);
}

// ---------------------------------------------------------------------------
// Pre-pass 1: split fp32 -> (hi, lo) bf16 planes. grid (EL/2048, 3)
// ---------------------------------------------------------------------------
struct SplitArgs { const float* src[3]; ushortT* dh[3]; ushortT* dl[3]; };
__global__ __launch_bounds__(256) void split_plain(SplitArgs a)
{
    const int z = blockIdx.y;
    const size_t i = ((size_t)blockIdx.x * 256 + threadIdx.x) * 8;
    const float* s = a.src[z];
    float4 v0 = *reinterpret_cast<const float4*>(s + i);
    float4 v1 = *reinterpret_cast<const float4*>(s + i + 4);
    float f[8] = {v0.x, v0.y, v0.z, v0.w, v1.x, v1.y, v1.z, v1.w};
    U8 h, l;
    #pragma unroll
    for (int j = 0; j < 8; ++j) split2(f[j], h.u[j], l.u[j]);
    *reinterpret_cast<short8*>(a.dh[z] + i) = h.v;
    *reinterpret_cast<short8*>(a.dl[z] + i) = l.v;
}

// ---------------------------------------------------------------------------
// Pre-pass 2: weights -> transposed split planes Wt[n][k]. grid (3, 96, 4)
// ---------------------------------------------------------------------------
struct WArgs { const float* src[4]; ushortT* dh[4]; ushortT* dl[4]; };
__global__ __launch_bounds__(256) void split_wt(WArgs a)
{
    const int n  = blockIdx.x * 256 + threadIdx.x;   // 0..767
    const int k0 = blockIdx.y * 8;
    const int z  = blockIdx.z;
    const float* W = a.src[z];
    U8 h, l;
    #pragma unroll
    for (int j = 0; j < 8; ++j) {
        float x = W[(size_t)(k0 + j) * DD + n];      // coalesced across lanes
        split2(x, h.u[j], l.u[j]);
    }
    *reinterpret_cast<short8*>(a.dh[z] + (size_t)n * DD + k0) = h.v;
    *reinterpret_cast<short8*>(a.dl[z] + (size_t)n * DD + k0) = l.v;
}

// ---------------------------------------------------------------------------
// bf16x3 MFMA GEMM: C[4096..][768] = A @ Bt^T + bias.
// A: split planes, hi at Ah, lo at Ah + apb bytes; row-major [M][768].
// Bt: split transposed planes [768 n][768 k], lo at +bpb bytes.
// LDS: one buffer per operand, [64 rows][hi 32 | lo 32] ushorts = 128B rows,
// 8 x 16B chunks, swizzle chunk ^= (row&7)  (bijective, 3-bit <-> 3-bit).
// Staging: global_load_lds w=16, linear dest, inverse-swizzled SOURCE addr.
// MODE 0: fp32 row-major out. MODE 1: split hi/lo bf16 row-major out.
// ---------------------------------------------------------------------------
template<int MODE>
__global__ __launch_bounds__(256) void gemm_mfma(const ushortT* __restrict__ Ah, size_t apb,
                                                 const ushortT* __restrict__ Bth, size_t bpb,
                                                 const float* __restrict__ bias,
                                                 float* __restrict__ outF,
                                                 ushortT* __restrict__ outH,
                                                 ushortT* __restrict__ outL)
{
    __shared__ ushortT As[64 * 64];   // 8 KB
    __shared__ ushortT Bs[64 * 64];   // 8 KB

    const int tid  = threadIdx.x;
    const int lane = tid & 63;
    const int w    = tid >> 6;
    const int g    = lane >> 4, c = lane & 15;
    const int n0   = blockIdx.x * 64;
    const int m0   = blockIdx.y * 64;

    // staging: wave w, issue t in {0,1}, lane i -> LDS byte w*2048 + t*1024 + i*16
    //   row = w*16 + t*8 + (i>>3)  (row&7 == i>>3 for both issues)
    //   LDS chunk = i&7 ; source chunk = (i&7) ^ (row&7)
    const int srow0 = w * 16 + (lane >> 3);
    const int csrc  = (lane & 7) ^ (lane >> 3);
    const size_t plA = (csrc >= 4) ? apb : 0;
    const size_t plB = (csrc >= 4) ? bpb : 0;
    const size_t abase = (size_t)(m0 + srow0) * (DD * 2) + plA + (size_t)(csrc & 3) * 16;
    const size_t bbase = (size_t)(n0 + srow0) * (DD * 2) + plB + (size_t)(csrc & 3) * 16;

    f32x4 acc[4] = {{0,0,0,0},{0,0,0,0},{0,0,0,0},{0,0,0,0}};

    // read offsets (ushort units): row*64 + chunk*8
    const int arow = w * 16 + c;
    const int ar7  = arow & 7;
    const int ahc  = g ^ ar7;                       // hi chunk; lo = ahc^4
    const int aoff_h = arow * 64 + ahc * 8;
    const int aoff_l = arow * 64 + (ahc ^ 4) * 8;

    for (int kt = 0; kt < DD / 32; ++kt) {
        const size_t ko = (size_t)kt * 64;          // 32 k-values = 64 bytes
        const char* asrc = (const char*)Ah  + abase + ko;
        const char* bsrc = (const char*)Bth + bbase + ko;
        gl2lds16(asrc,            &As[w * 1024]);
        gl2lds16(asrc + 8 * (DD * 2), &As[w * 1024 + 512]);
        gl2lds16(bsrc,            &Bs[w * 1024]);
        gl2lds16(bsrc + 8 * (DD * 2), &Bs[w * 1024 + 512]);
        __syncthreads();                            // drains vmcnt before reads

        const short8 a_h = *reinterpret_cast<const short8*>(&As[aoff_h]);
        const short8 a_l = *reinterpret_cast<const short8*>(&As[aoff_l]);
        #pragma unroll
        for (int nf = 0; nf < 4; ++nf) {
            const int brow = nf * 16 + c;
            const int bhc  = g ^ (brow & 7);
            const short8 b_h = *reinterpret_cast<const short8*>(&Bs[brow * 64 + bhc * 8]);
            const short8 b_l = *reinterpret_cast<const short8*>(&Bs[brow * 64 + (bhc ^ 4) * 8]);
            acc[nf] = MFMA(a_h, b_h, acc[nf]);
            acc[nf] = MFMA(a_l, b_h, acc[nf]);
            acc[nf] = MFMA(a_h, b_l, acc[nf]);
        }
        __syncthreads();
    }

    // epilogue: C row = m0 + w*16 + 4g + r, col = n0 + nf*16 + c
    #pragma unroll
    for (int nf = 0; nf < 4; ++nf) {
        const int n = n0 + nf * 16 + c;
        const float bz = bias[n];
        #pragma unroll
        for (int r = 0; r < 4; ++r) {
            const int m = m0 + w * 16 + 4 * g + r;
            const float vv = acc[nf][r] + bz;
            if (MODE == 0) {
                outF[(size_t)m * DD + n] = vv;
            } else {
                unsigned short hh, ll;
                split2(vv, hh, ll);
                outH[(size_t)m * DD + n] = hh;
                outL[(size_t)m * DD + n] = ll;
            }
        }
    }
}

// ---------------------------------------------------------------------------
// Flash attention, bf16x3 MFMA, pre-split inputs (row-major [4096][768] planes)
// ---------------------------------------------------------------------------
__global__ __launch_bounds__(256) void attn_mfma(const ushortT* __restrict__ Qh_g,
                                                 const ushortT* __restrict__ Ql_g,
                                                 const ushortT* __restrict__ Kh_g,
                                                 const ushortT* __restrict__ Kl_g,
                                                 const ushortT* __restrict__ Vh_g,
                                                 const ushortT* __restrict__ Vl_g,
                                                 const float* __restrict__ mask,
                                                 ushortT* __restrict__ Oh_g,
                                                 ushortT* __restrict__ Ol_g)
{
    __shared__ unsigned short Kh[32 * 64];
    __shared__ unsigned short Kl[32 * 64];
    __shared__ unsigned short Vt[64 * 64];
    __shared__ unsigned short Pb[4 * 16 * 64];
    __shared__ float mterm[KT];

    const int tid = threadIdx.x;
    const int l   = tid & 63;
    const int w   = tid >> 6;
    const int g   = l >> 4;
    const int c   = l & 15;
    const int bh  = blockIdx.y;
    const int b   = bh / NH;
    const int h   = bh % NH;
    const int r0  = blockIdx.x * QT;

    // Q frags: row = b*LL + r0 + w*16 + c, cols h*64 + 32*hf + 8*g (+j)
    short8 qh[2], ql[2];
    {
        const size_t qoff = (size_t)(b * LL + r0 + w * 16 + c) * DD + h * 64 + 8 * g;
        qh[0] = *reinterpret_cast<const short8*>(Qh_g + qoff);
        qh[1] = *reinterpret_cast<const short8*>(Qh_g + qoff + 32);
        ql[0] = *reinterpret_cast<const short8*>(Ql_g + qoff);
        ql[1] = *reinterpret_cast<const short8*>(Ql_g + qoff + 32);
    }

    f32x4 Oa[4] = {{0,0,0,0},{0,0,0,0},{0,0,0,0},{0,0,0,0}};
    float mrun[4] = {-1e30f,-1e30f,-1e30f,-1e30f};
    float lrun[4] = {0.f,0.f,0.f,0.f};

    const int skey = tid >> 3;        // staging: key 0..31
    const int sd0  = (tid & 7) * 8;   // staging: d group

    for (int kt = 0; kt < NTILES; ++kt) {
        __syncthreads();
        // ---- stage K tile (pre-split, b128 copy) ----
        {
            const size_t ko = (size_t)(b * LL + kt * KT + skey) * DD + h * 64 + sd0;
            const short8 hh = *reinterpret_cast<const short8*>(Kh_g + ko);
            const short8 lo = *reinterpret_cast<const short8*>(Kl_g + ko);
            const int idx = skey * 64 + (((sd0 * 2) ^ swz(skey)) >> 1);
            *reinterpret_cast<short8*>(&Kh[idx]) = hh;
            *reinterpret_cast<short8*>(&Kl[idx]) = lo;
        }
        // ---- stage V tile transposed ----
        {
            const size_t vo = (size_t)(b * LL + kt * KT + skey) * DD + h * 64 + sd0;
            U8 vh8, vl8;
            vh8.v = *reinterpret_cast<const short8*>(Vh_g + vo);
            vl8.v = *reinterpret_cast<const short8*>(Vl_g + vo);
            #pragma unroll
            for (int j = 0; j < 8; ++j) {
                const int d = sd0 + j;
                const int s = swz(d);
                Vt[d * 64 + (((2 * skey) ^ s) >> 1)]      = vh8.u[j];
                Vt[d * 64 + (((64 + 2 * skey) ^ s) >> 1)] = vl8.u[j];
            }
        }
        if (tid < KT)
            mterm[tid] = (1.0f - mask[(size_t)b * LL + kt * KT + tid]) * -99999.0f;
        __syncthreads();

        // ---- scores (x 0.125 scale folded post-MFMA) ----
        f32x4 s[2];
        #pragma unroll
        for (int th = 0; th < 2; ++th) {
            const int row = th * 16 + c;
            const int sw = swz(row);
            const short8 kh0 = *reinterpret_cast<const short8*>(&Kh[row * 64 + (((16 * g     ) ^ sw) >> 1)]);
            const short8 kh1 = *reinterpret_cast<const short8*>(&Kh[row * 64 + (((16 * g + 64) ^ sw) >> 1)]);
            const short8 kl0 = *reinterpret_cast<const short8*>(&Kl[row * 64 + (((16 * g     ) ^ sw) >> 1)]);
            const short8 kl1 = *reinterpret_cast<const short8*>(&Kl[row * 64 + (((16 * g + 64) ^ sw) >> 1)]);
            f32x4 a = {0,0,0,0};
            a = MFMA(qh[0], kh0, a); a = MFMA(qh[1], kh1, a);
            a = MFMA(ql[0], kh0, a); a = MFMA(ql[1], kh1, a);
            a = MFMA(qh[0], kl0, a); a = MFMA(qh[1], kl1, a);
            const float mt = mterm[th * 16 + c];
            #pragma unroll
            for (int r = 0; r < 4; ++r) a[r] = fmaf(a[r], 0.125f, mt);
            s[th] = a;
        }

        // ---- online softmax (rows 4g+r, reduce across 16-lane group) ----
        float pexp[2][4];
        #pragma unroll
        for (int r = 0; r < 4; ++r) {
            float tm = fmaxf(s[0][r], s[1][r]);
            #pragma unroll
            for (int o = 1; o < 16; o <<= 1) tm = fmaxf(tm, __shfl_xor(tm, o));
            const float mn = fmaxf(mrun[r], tm);
            const float scale = __expf(mrun[r] - mn);
            const float p0 = __expf(s[0][r] - mn);
            const float p1 = __expf(s[1][r] - mn);
            float rs = p0 + p1;
            #pragma unroll
            for (int o = 1; o < 16; o <<= 1) rs += __shfl_xor(rs, o);
            lrun[r] = lrun[r] * scale + rs;
            mrun[r] = mn;
            pexp[0][r] = p0; pexp[1][r] = p1;
            #pragma unroll
            for (int n = 0; n < 4; ++n) Oa[n][r] *= scale;
        }

        // ---- P -> per-wave LDS (hi/lo) ----
        unsigned short* Pw = &Pb[w * 16 * 64];
        #pragma unroll
        for (int th = 0; th < 2; ++th)
            #pragma unroll
            for (int r = 0; r < 4; ++r) {
                const int row = 4 * g + r;
                const int sw2 = swz(row);
                unsigned short h_, l_;
                split2(pexp[th][r], h_, l_);
                const int keyb = 2 * (th * 16 + c);
                Pw[row * 64 + ((keyb ^ sw2) >> 1)]        = h_;
                Pw[row * 64 + (((64 + keyb) ^ sw2) >> 1)] = l_;
            }
        asm volatile("s_waitcnt lgkmcnt(0)" ::: "memory");

        // ---- PV ----
        {
            const int sw2 = swz(c);
            const short8 pa_h = *reinterpret_cast<const short8*>(&Pw[c * 64 + (((16 * g     ) ^ sw2) >> 1)]);
            const short8 pa_l = *reinterpret_cast<const short8*>(&Pw[c * 64 + (((64 + 16 * g) ^ sw2) >> 1)]);
            #pragma unroll
            for (int n = 0; n < 4; ++n) {
                const int vrow = 16 * n + c;
                const int sv = swz(vrow);
                const short8 vh = *reinterpret_cast<const short8*>(&Vt[vrow * 64 + (((16 * g     ) ^ sv) >> 1)]);
                const short8 vl = *reinterpret_cast<const short8*>(&Vt[vrow * 64 + (((64 + 16 * g) ^ sv) >> 1)]);
                Oa[n] = MFMA(pa_h, vh, Oa[n]);
                Oa[n] = MFMA(pa_h, vl, Oa[n]);
                Oa[n] = MFMA(pa_l, vh, Oa[n]);
            }
        }
    }

    // ---- epilogue: O / l, store split hi/lo bf16 row-major ----
    #pragma unroll
    for (int r = 0; r < 4; ++r) {
        const float inv = 1.0f / lrun[r];
        const int row = b * LL + r0 + w * 16 + 4 * g + r;
        ushortT* oh = Oh_g + (size_t)row * DD + h * 64;
        ushortT* ol = Ol_g + (size_t)row * DD + h * 64;
        #pragma unroll
        for (int n = 0; n < 4; ++n) {
            unsigned short hh, ll;
            split2(Oa[n][r] * inv, hh, ll);
            oh[16 * n + c] = hh;
            ol[16 * n + c] = ll;
        }
    }
}

// ---------------------------------------------------------------------------
extern "C" void kernel_launch(void* const* d_in, const int* in_sizes, int n_in,
                              void* d_out, int out_size, void* d_ws, size_t ws_size,
                              hipStream_t stream)
{
    const float* q    = (const float*)d_in[0];
    const float* k    = (const float*)d_in[1];
    const float* v    = (const float*)d_in[2];
    const float* amask= (const float*)d_in[3];
    const float* Wq   = (const float*)d_in[4];
    const float* bq   = (const float*)d_in[5];
    const float* Wk   = (const float*)d_in[6];
    const float* bk   = (const float*)d_in[7];
    const float* Wv   = (const float*)d_in[8];
    const float* bv   = (const float*)d_in[9];
    const float* Wo   = (const float*)d_in[10];
    const float* bo   = (const float*)d_in[11];
    float* out = (float*)d_out;

    // ws map (ushort units): 6 input planes | 8 weight planes | 6 proj planes
    // Oh/Ol alias the q/k input planes (dead after the projection GEMMs).
    ushortT* W0 = (ushortT*)d_ws;
    ushortT* qh = W0;            ushortT* ql = W0 + (size_t)EL;
    ushortT* kh = W0 + 2*(size_t)EL;  ushortT* kl = W0 + 3*(size_t)EL;
    ushortT* vh = W0 + 4*(size_t)EL;  ushortT* vl = W0 + 5*(size_t)EL;
    ushortT* wb = W0 + 6*(size_t)EL;
    ushortT* wqh = wb;            ushortT* wql = wb + (size_t)WEL;
    ushortT* wkh = wb + 2*(size_t)WEL; ushortT* wkl = wb + 3*(size_t)WEL;
    ushortT* wvh = wb + 4*(size_t)WEL; ushortT* wvl = wb + 5*(size_t)WEL;
    ushortT* woh = wb + 6*(size_t)WEL; ushortT* wol = wb + 7*(size_t)WEL;
    ushortT* pb = wb + 8*(size_t)WEL;
    ushortT* Qph = pb;            ushortT* Qpl = pb + (size_t)EL;
    ushortT* Kph = pb + 2*(size_t)EL;  ushortT* Kpl = pb + 3*(size_t)EL;
    ushortT* Vph = pb + 4*(size_t)EL;  ushortT* Vpl = pb + 5*(size_t)EL;
    ushortT* Oh = W0;             ushortT* Ol = W0 + (size_t)EL;   // alias

    const size_t APB = (size_t)EL * 2;    // activation hi->lo plane gap, bytes
    const size_t WPB = (size_t)WEL * 2;   // weight hi->lo plane gap, bytes

    // pre-pass splits
    SplitArgs sa;
    sa.src[0] = q; sa.src[1] = k; sa.src[2] = v;
    sa.dh[0] = qh; sa.dh[1] = kh; sa.dh[2] = vh;
    sa.dl[0] = ql; sa.dl[1] = kl; sa.dl[2] = vl;
    split_plain<<<dim3(EL / 2048, 3), 256, 0, stream>>>(sa);

    WArgs wa;
    wa.src[0] = Wq; wa.src[1] = Wk; wa.src[2] = Wv; wa.src[3] = Wo;
    wa.dh[0] = wqh; wa.dh[1] = wkh; wa.dh[2] = wvh; wa.dh[3] = woh;
    wa.dl[0] = wql; wa.dl[1] = wkl; wa.dl[2] = wvl; wa.dl[3] = wol;
    split_wt<<<dim3(3, 96, 4), 256, 0, stream>>>(wa);

    // projections (split bf16 out)
    dim3 ggrid(DD / 64, 4096 / 64);   // (12, 64)
    gemm_mfma<1><<<ggrid, 256, 0, stream>>>(qh, APB, wqh, WPB, bq, nullptr, Qph, Qpl);
    gemm_mfma<1><<<ggrid, 256, 0, stream>>>(kh, APB, wkh, WPB, bk, nullptr, Kph, Kpl);
    gemm_mfma<1><<<ggrid, 256, 0, stream>>>(vh, APB, wvh, WPB, bv, nullptr, Vph, Vpl);

    // attention
    dim3 agrid(LL / QT, BB * NH);     // (32, 24)
    attn_mfma<<<agrid, 256, 0, stream>>>(Qph, Qpl, Kph, Kpl, Vph, Vpl, amask, Oh, Ol);

    // output projection (fp32 out)
    gemm_mfma<0><<<ggrid, 256, 0, stream>>>(Oh, APB, woh, WPB, bo, out, nullptr, nullptr);
}

// Round 8
// 387.969 us; speedup vs baseline: 5.2362x; 1.0586x over previous
//
#include <hip/hip_runtime.h>
#include <math.h>

#define BB 2
#define LL 2048
#define DD 768
#define NH 12
#define HD 64
#define EL (4096*768)     // elements of one [4096][768] plane
#define WEL (768*768)     // elements of one weight plane

typedef __attribute__((ext_vector_type(8))) short short8;   // 8 bf16
typedef __attribute__((ext_vector_type(4))) float f32x4;
typedef __attribute__((ext_vector_type(16))) float f32x16;
typedef __attribute__((ext_vector_type(4))) unsigned int u32x4;
typedef unsigned short ushortT;

union U8 { unsigned short u[8]; short8 v; };
union UB { u32x4 u; short8 v; };

#define MFMA(a,b,c)   __builtin_amdgcn_mfma_f32_16x16x32_bf16((a),(b),(c),0,0,0)
#define MFMA32(a,b,c) __builtin_amdgcn_mfma_f32_32x32x16_bf16((a),(b),(c),0,0,0)

__device__ inline unsigned short f2bf(float x) {          // RNE f32 -> bf16 bits
    unsigned int u = __float_as_uint(x);
    unsigned int r = (u + 0x7fffu + ((u >> 16) & 1u)) >> 16;
    return (unsigned short)r;
}
__device__ inline float bf2f(unsigned short s) {
    return __uint_as_float(((unsigned int)s) << 16);
}
__device__ inline void split2(float x, unsigned short& h, unsigned short& l) {
    h = f2bf(x);
    l = f2bf(x - bf2f(h));
}
__device__ inline int swz(int row) { return (((row & 7) ^ ((row >> 3) & 7)) << 4); }

__device__ inline void gl2lds16(const void* g, void* l) {
    __builtin_amdgcn_global_load_lds((__attribute__((address_space(1))) const void*)g,
                                     (__attribute__((address_space(3))) void*)l, 16, 0, 0);
}

// ---------------------------------------------------------------------------
// Pre-pass 1: split fp32 -> (hi, lo) bf16 planes. grid (EL/2048, 3)
// ---------------------------------------------------------------------------
struct SplitArgs { const float* src[3]; ushortT* dh[3]; ushortT* dl[3]; };
__global__ __launch_bounds__(256) void split_plain(SplitArgs a)
{
    const int z = blockIdx.y;
    const size_t i = ((size_t)blockIdx.x * 256 + threadIdx.x) * 8;
    const float* s = a.src[z];
    float4 v0 = *reinterpret_cast<const float4*>(s + i);
    float4 v1 = *reinterpret_cast<const float4*>(s + i + 4);
    float f[8] = {v0.x, v0.y, v0.z, v0.w, v1.x, v1.y, v1.z, v1.w};
    U8 h, l;
    #pragma unroll
    for (int j = 0; j < 8; ++j) split2(f[j], h.u[j], l.u[j]);
    *reinterpret_cast<short8*>(a.dh[z] + i) = h.v;
    *reinterpret_cast<short8*>(a.dl[z] + i) = l.v;
}

// ---------------------------------------------------------------------------
// Pre-pass 2: weights -> transposed split planes Wt[n][k], x scale. grid (3,96,4)
// ---------------------------------------------------------------------------
struct WArgs { const float* src[4]; ushortT* dh[4]; ushortT* dl[4]; float scale[4]; };
__global__ __launch_bounds__(256) void split_wt(WArgs a)
{
    const int n  = blockIdx.x * 256 + threadIdx.x;   // 0..767
    const int k0 = blockIdx.y * 8;
    const int z  = blockIdx.z;
    const float* W = a.src[z];
    const float sc = a.scale[z];
    U8 h, l;
    #pragma unroll
    for (int j = 0; j < 8; ++j) {
        float x = W[(size_t)(k0 + j) * DD + n] * sc;  // coalesced across lanes
        split2(x, h.u[j], l.u[j]);
    }
    *reinterpret_cast<short8*>(a.dh[z] + (size_t)n * DD + k0) = h.v;
    *reinterpret_cast<short8*>(a.dl[z] + (size_t)n * DD + k0) = l.v;
}

// ---------------------------------------------------------------------------
// bf16x3 MFMA GEMM (unchanged from R6): C = A @ Bt^T + bias*bscale.
// ---------------------------------------------------------------------------
template<int MODE>
__global__ __launch_bounds__(256) void gemm_mfma(const ushortT* __restrict__ Ah, size_t apb,
                                                 const ushortT* __restrict__ Bth, size_t bpb,
                                                 const float* __restrict__ bias, float bscale,
                                                 float* __restrict__ outF,
                                                 ushortT* __restrict__ outH,
                                                 ushortT* __restrict__ outL)
{
    __shared__ ushortT As[64 * 64];   // 8 KB
    __shared__ ushortT Bs[64 * 64];   // 8 KB

    const int tid  = threadIdx.x;
    const int lane = tid & 63;
    const int w    = tid >> 6;
    const int g    = lane >> 4, c = lane & 15;
    const int n0   = blockIdx.x * 64;
    const int m0   = blockIdx.y * 64;

    const int srow0 = w * 16 + (lane >> 3);
    const int csrc  = (lane & 7) ^ (lane >> 3);
    const size_t plA = (csrc >= 4) ? apb : 0;
    const size_t plB = (csrc >= 4) ? bpb : 0;
    const size_t abase = (size_t)(m0 + srow0) * (DD * 2) + plA + (size_t)(csrc & 3) * 16;
    const size_t bbase = (size_t)(n0 + srow0) * (DD * 2) + plB + (size_t)(csrc & 3) * 16;

    f32x4 acc[4] = {{0,0,0,0},{0,0,0,0},{0,0,0,0},{0,0,0,0}};

    const int arow = w * 16 + c;
    const int ahc  = g ^ (arow & 7);
    const int aoff_h = arow * 64 + ahc * 8;
    const int aoff_l = arow * 64 + (ahc ^ 4) * 8;

    for (int kt = 0; kt < DD / 32; ++kt) {
        const size_t ko = (size_t)kt * 64;
        const char* asrc = (const char*)Ah  + abase + ko;
        const char* bsrc = (const char*)Bth + bbase + ko;
        gl2lds16(asrc,                &As[w * 1024]);
        gl2lds16(asrc + 8 * (DD * 2), &As[w * 1024 + 512]);
        gl2lds16(bsrc,                &Bs[w * 1024]);
        gl2lds16(bsrc + 8 * (DD * 2), &Bs[w * 1024 + 512]);
        __syncthreads();

        const short8 a_h = *reinterpret_cast<const short8*>(&As[aoff_h]);
        const short8 a_l = *reinterpret_cast<const short8*>(&As[aoff_l]);
        #pragma unroll
        for (int nf = 0; nf < 4; ++nf) {
            const int brow = nf * 16 + c;
            const int bhc  = g ^ (brow & 7);
            const short8 b_h = *reinterpret_cast<const short8*>(&Bs[brow * 64 + bhc * 8]);
            const short8 b_l = *reinterpret_cast<const short8*>(&Bs[brow * 64 + (bhc ^ 4) * 8]);
            acc[nf] = MFMA(a_h, b_h, acc[nf]);
            acc[nf] = MFMA(a_l, b_h, acc[nf]);
            acc[nf] = MFMA(a_h, b_l, acc[nf]);
        }
        __syncthreads();
    }

    #pragma unroll
    for (int nf = 0; nf < 4; ++nf) {
        const int n = n0 + nf * 16 + c;
        const float bz = bias[n] * bscale;
        #pragma unroll
        for (int r = 0; r < 4; ++r) {
            const int m = m0 + w * 16 + 4 * g + r;
            const float vv = acc[nf][r] + bz;
            if (MODE == 0) {
                outF[(size_t)m * DD + n] = vv;
            } else {
                unsigned short hh, ll;
                split2(vv, hh, ll);
                outH[(size_t)m * DD + n] = hh;
                outL[(size_t)m * DD + n] = ll;
            }
        }
    }
}

// ---------------------------------------------------------------------------
// Flash attention, swapped-QK^T 32x32 structure, bf16x3, in-register softmax.
// Block: 128 thr = 2 waves; wave owns 32 q-rows. Grid (LL/64, BB*NH).
// S^T = mfma32(K, Q): lane -> q col = lane&31, keys = (r&3)+8(r>>2)+4(lane>>5).
// O^T = mfma32(V^T, P^T) accumulated with online-softmax rescale.
// Q is pre-scaled by 1/8 (folded into Wq/bq at split time).
// ---------------------------------------------------------------------------
__global__ __launch_bounds__(128) void attn_mfma(const ushortT* __restrict__ Qh_g,
                                                 const ushortT* __restrict__ Ql_g,
                                                 const ushortT* __restrict__ Kh_g,
                                                 const ushortT* __restrict__ Kl_g,
                                                 const ushortT* __restrict__ Vh_g,
                                                 const ushortT* __restrict__ Vl_g,
                                                 const float* __restrict__ mask,
                                                 ushortT* __restrict__ Oh_g,
                                                 ushortT* __restrict__ Ol_g)
{
    __shared__ ushortT Kh[32 * 64];   // [key][d], 128B rows, chunk ^= key&7
    __shared__ ushortT Kl[32 * 64];
    __shared__ ushortT Vt[64 * 64];   // [d][key hi 32 | key lo 32], swz(d) rows
    __shared__ float mterm[32];

    const int tid  = threadIdx.x;
    const int lane = tid & 63;
    const int w    = tid >> 6;        // 2 waves
    const int qc   = lane & 31;       // q column
    const int h5   = lane >> 5;
    const int bh   = blockIdx.y;
    const int b    = bh / NH;
    const int h    = bh % NH;
    const int r0   = blockIdx.x * 64;
    const int qrow = r0 + w * 32 + qc;

    // ---- Q B-frags: col q = qc, k d = 8*h5 + j + 16*ks  (pre-scaled by 1/8)
    short8 qbh[4], qbl[4];
    {
        const size_t qoff = (size_t)(b * LL + qrow) * DD + h * 64;
        #pragma unroll
        for (int ks = 0; ks < 4; ++ks) {
            const int d0 = 8 * h5 + 16 * ks;
            qbh[ks] = *reinterpret_cast<const short8*>(Qh_g + qoff + d0);
            qbl[ks] = *reinterpret_cast<const short8*>(Ql_g + qoff + d0);
        }
    }

    f32x16 Oa[2];
    #pragma unroll
    for (int m = 0; m < 2; ++m)
        #pragma unroll
        for (int r = 0; r < 16; ++r) Oa[m][r] = 0.f;
    float mrun = -1e30f, lrun = 0.f;

    // staging geometry
    const int skey = tid >> 2;              // V: key 0..31
    const int sd0v = (tid & 3) * 16;        // V: 16 d per thread
    ushortT* kdst = w ? Kl : Kh;            // wave0 -> Kh, wave1 -> Kl
    const ushortT* ksrcp = w ? Kl_g : Kh_g;
    const int krow_l = lane >> 3;           // row within 8-row issue group
    const int kcsrc  = (lane & 7) ^ krow_l; // inverse-swizzled source chunk

    for (int kt = 0; kt < LL / 32; ++kt) {
        __syncthreads();
        // ---- K staging: global_load_lds, 4 issues of 8 rows per wave ----
        {
            const size_t kbase = (size_t)(b * LL + kt * 32 + krow_l) * DD + h * 64 + kcsrc * 8;
            #pragma unroll
            for (int t = 0; t < 4; ++t)
                gl2lds16(ksrcp + kbase + (size_t)(8 * t) * DD, kdst + t * 512);
        }
        // ---- V staging: reg load + scalar transpose writes ----
        {
            const size_t vo = (size_t)(b * LL + kt * 32 + skey) * DD + h * 64 + sd0v;
            U8 a0, a1, b0, b1;
            a0.v = *reinterpret_cast<const short8*>(Vh_g + vo);
            a1.v = *reinterpret_cast<const short8*>(Vh_g + vo + 8);
            b0.v = *reinterpret_cast<const short8*>(Vl_g + vo);
            b1.v = *reinterpret_cast<const short8*>(Vl_g + vo + 8);
            #pragma unroll
            for (int j = 0; j < 8; ++j) {
                int d = sd0v + j; int s = swz(d);
                Vt[d * 64 + (((2 * skey) ^ s) >> 1)]      = a0.u[j];
                Vt[d * 64 + (((64 + 2 * skey) ^ s) >> 1)] = b0.u[j];
                d = sd0v + 8 + j; s = swz(d);
                Vt[d * 64 + (((2 * skey) ^ s) >> 1)]      = a1.u[j];
                Vt[d * 64 + (((64 + 2 * skey) ^ s) >> 1)] = b1.u[j];
            }
        }
        if (tid < 32)
            mterm[tid] = (1.0f - mask[(size_t)b * LL + kt * 32 + tid]) * -99999.0f;
        __syncthreads();

        // ---- S^T = K . Q^T  (bf16x3, 4 d-steps) ----
        f32x16 sa;
        #pragma unroll
        for (int r = 0; r < 16; ++r) sa[r] = 0.f;
        #pragma unroll
        for (int ks = 0; ks < 4; ++ks) {
            const int ch = (h5 + 2 * ks) ^ (qc & 7);   // key = lane&31 = qc here
            const short8 kfh = *reinterpret_cast<const short8*>(&Kh[qc * 64 + ch * 8]);
            const short8 kfl = *reinterpret_cast<const short8*>(&Kl[qc * 64 + ch * 8]);
            sa = MFMA32(kfh, qbh[ks], sa);
            sa = MFMA32(kfl, qbh[ks], sa);
            sa = MFMA32(kfh, qbl[ks], sa);
        }

        // ---- in-register online softmax (lane owns q-row qc) ----
        float sm[16];
        #pragma unroll
        for (int r = 0; r < 16; ++r)
            sm[r] = sa[r] + mterm[(r & 3) + 8 * (r >> 2) + 4 * h5];
        float tm = sm[0];
        #pragma unroll
        for (int r = 1; r < 16; ++r) tm = fmaxf(tm, sm[r]);
        tm = fmaxf(tm, __shfl_xor(tm, 32));
        const float mn = fmaxf(mrun, tm);
        const float scale = __expf(mrun - mn);
        float p[16];
        float rs = 0.f;
        #pragma unroll
        for (int r = 0; r < 16; ++r) { p[r] = __expf(sm[r] - mn); rs += p[r]; }
        rs += __shfl_xor(rs, 32);
        lrun = lrun * scale + rs;
        mrun = mn;
        #pragma unroll
        for (int m = 0; m < 2; ++m)
            #pragma unroll
            for (int r = 0; r < 16; ++r) Oa[m][r] *= scale;

        // ---- P -> bf16 packs + cross-half exchange (registers only) ----
        // pack s covers keys: s=0:{4h5+0,1} 1:{4h5+2,3} 2:{8+4h5+0,1} 3:{8+4h5+2,3}
        //                     4..7: same +16
        unsigned int pkh[8], pkl[8], xph[8], xpl[8];
        #pragma unroll
        for (int s2 = 0; s2 < 8; ++s2) {
            unsigned short h0, l0, h1, l1;
            split2(p[2 * s2],     h0, l0);
            split2(p[2 * s2 + 1], h1, l1);
            pkh[s2] = (unsigned int)h0 | ((unsigned int)h1 << 16);
            pkl[s2] = (unsigned int)l0 | ((unsigned int)l1 << 16);
            xph[s2] = __shfl_xor(pkh[s2], 32);
            xpl[s2] = __shfl_xor(pkl[s2], 32);
        }
        // B-frag[ks2]: keys 8*h5 + j + 16*ks2
        UB pbh[2], pbl[2];
        if (h5 == 0) {
            pbh[0].u = (u32x4){pkh[0], pkh[1], xph[0], xph[1]};
            pbl[0].u = (u32x4){pkl[0], pkl[1], xpl[0], xpl[1]};
            pbh[1].u = (u32x4){pkh[4], pkh[5], xph[4], xph[5]};
            pbl[1].u = (u32x4){pkl[4], pkl[5], xpl[4], xpl[5]};
        } else {
            pbh[0].u = (u32x4){xph[2], xph[3], pkh[2], pkh[3]};
            pbl[0].u = (u32x4){xpl[2], xpl[3], pkl[2], pkl[3]};
            pbh[1].u = (u32x4){xph[6], xph[7], pkh[6], pkh[7]};
            pbl[1].u = (u32x4){xpl[6], xpl[7], pkl[6], pkl[7]};
        }

        // ---- O^T += V^T . P^T  (bf16x3, 2 d-blocks x 2 key-steps) ----
        #pragma unroll
        for (int m = 0; m < 2; ++m) {
            const int d  = qc + 32 * m;      // A row
            const int sv = swz(d);
            #pragma unroll
            for (int ks2 = 0; ks2 < 2; ++ks2) {
                const int bc = 16 * h5 + 32 * ks2;     // hi-plane byte col
                const short8 vfh = *reinterpret_cast<const short8*>(&Vt[d * 64 + ((bc ^ sv) >> 1)]);
                const short8 vfl = *reinterpret_cast<const short8*>(&Vt[d * 64 + (((64 + bc) ^ sv) >> 1)]);
                Oa[m] = MFMA32(vfh, pbh[ks2].v, Oa[m]);
                Oa[m] = MFMA32(vfl, pbh[ks2].v, Oa[m]);
                Oa[m] = MFMA32(vfh, pbl[ks2].v, Oa[m]);
            }
        }
    }

    // ---- epilogue: O^T / l, split-store bf16 hi/lo (scalar stores) ----
    const float inv = 1.0f / lrun;
    const size_t obase = (size_t)(b * LL + qrow) * DD + h * 64;
    #pragma unroll
    for (int m = 0; m < 2; ++m)
        #pragma unroll
        for (int r = 0; r < 16; ++r) {
            const int d = (r & 3) + 8 * (r >> 2) + 4 * h5 + 32 * m;
            unsigned short hh, ll;
            split2(Oa[m][r] * inv, hh, ll);
            Oh_g[obase + d] = hh;
            Ol_g[obase + d] = ll;
        }
}

// ---------------------------------------------------------------------------
extern "C" void kernel_launch(void* const* d_in, const int* in_sizes, int n_in,
                              void* d_out, int out_size, void* d_ws, size_t ws_size,
                              hipStream_t stream)
{
    const float* q    = (const float*)d_in[0];
    const float* k    = (const float*)d_in[1];
    const float* v    = (const float*)d_in[2];
    const float* amask= (const float*)d_in[3];
    const float* Wq   = (const float*)d_in[4];
    const float* bq   = (const float*)d_in[5];
    const float* Wk   = (const float*)d_in[6];
    const float* bk   = (const float*)d_in[7];
    const float* Wv   = (const float*)d_in[8];
    const float* bv   = (const float*)d_in[9];
    const float* Wo   = (const float*)d_in[10];
    const float* bo   = (const float*)d_in[11];
    float* out = (float*)d_out;

    // ws map (ushort units): 6 input planes | 8 weight planes | 6 proj planes
    ushortT* W0 = (ushortT*)d_ws;
    ushortT* qh = W0;                 ushortT* ql = W0 + (size_t)EL;
    ushortT* kh = W0 + 2*(size_t)EL;  ushortT* kl = W0 + 3*(size_t)EL;
    ushortT* vh = W0 + 4*(size_t)EL;  ushortT* vl = W0 + 5*(size_t)EL;
    ushortT* wb = W0 + 6*(size_t)EL;
    ushortT* wqh = wb;                 ushortT* wql = wb + (size_t)WEL;
    ushortT* wkh = wb + 2*(size_t)WEL; ushortT* wkl = wb + 3*(size_t)WEL;
    ushortT* wvh = wb + 4*(size_t)WEL; ushortT* wvl = wb + 5*(size_t)WEL;
    ushortT* woh = wb + 6*(size_t)WEL; ushortT* wol = wb + 7*(size_t)WEL;
    ushortT* pb = wb + 8*(size_t)WEL;
    ushortT* Qph = pb;                 ushortT* Qpl = pb + (size_t)EL;
    ushortT* Kph = pb + 2*(size_t)EL;  ushortT* Kpl = pb + 3*(size_t)EL;
    ushortT* Vph = pb + 4*(size_t)EL;  ushortT* Vpl = pb + 5*(size_t)EL;
    ushortT* Oh = W0;                  ushortT* Ol = W0 + (size_t)EL;   // alias q/k

    const size_t APB = (size_t)EL * 2;    // activation hi->lo plane gap, bytes
    const size_t WPB = (size_t)WEL * 2;   // weight hi->lo plane gap, bytes

    SplitArgs sa;
    sa.src[0] = q; sa.src[1] = k; sa.src[2] = v;
    sa.dh[0] = qh; sa.dh[1] = kh; sa.dh[2] = vh;
    sa.dl[0] = ql; sa.dl[1] = kl; sa.dl[2] = vl;
    split_plain<<<dim3(EL / 2048, 3), 256, 0, stream>>>(sa);

    WArgs wa;
    wa.src[0] = Wq; wa.src[1] = Wk; wa.src[2] = Wv; wa.src[3] = Wo;
    wa.dh[0] = wqh; wa.dh[1] = wkh; wa.dh[2] = wvh; wa.dh[3] = woh;
    wa.dl[0] = wql; wa.dl[1] = wkl; wa.dl[2] = wvl; wa.dl[3] = wol;
    wa.scale[0] = 0.125f; wa.scale[1] = 1.f; wa.scale[2] = 1.f; wa.scale[3] = 1.f;
    split_wt<<<dim3(3, 96, 4), 256, 0, stream>>>(wa);

    dim3 ggrid(DD / 64, 4096 / 64);   // (12, 64)
    gemm_mfma<1><<<ggrid, 256, 0, stream>>>(qh, APB, wqh, WPB, bq, 0.125f, nullptr, Qph, Qpl);
    gemm_mfma<1><<<ggrid, 256, 0, stream>>>(kh, APB, wkh, WPB, bk, 1.0f,   nullptr, Kph, Kpl);
    gemm_mfma<1><<<ggrid, 256, 0, stream>>>(vh, APB, wvh, WPB, bv, 1.0f,   nullptr, Vph, Vpl);

    dim3 agrid(LL / 64, BB * NH);     // (32, 24)
    attn_mfma<<<agrid, 128, 0, stream>>>(Qph, Qpl, Kph, Kpl, Vph, Vpl, amask, Oh, Ol);

    gemm_mfma<0><<<ggrid, 256, 0, stream>>>(Oh, APB, woh, WPB, bo, 1.0f, out, nullptr, nullptr);
}

// Round 9
// 384.805 us; speedup vs baseline: 5.2793x; 1.0082x over previous
//
#include <hip/hip_runtime.h>
#include <math.h>

#define BB 2
#define LL 2048
#define DD 768
#define NH 12
#define HD 64
#define NT (LL/32)        // key tiles
#define EL (4096*768)     // elements of one [4096][768] plane
#define WEL (768*768)     // elements of one weight plane

typedef __attribute__((ext_vector_type(8))) short short8;   // 8 bf16
typedef __attribute__((ext_vector_type(4))) float f32x4;
typedef __attribute__((ext_vector_type(16))) float f32x16;
typedef __attribute__((ext_vector_type(4))) unsigned int u32x4;
typedef unsigned short ushortT;

union U8 { unsigned short u[8]; short8 v; };
union UB { u32x4 u; short8 v; };

#define MFMA(a,b,c)   __builtin_amdgcn_mfma_f32_16x16x32_bf16((a),(b),(c),0,0,0)
#define MFMA32(a,b,c) __builtin_amdgcn_mfma_f32_32x32x16_bf16((a),(b),(c),0,0,0)

__device__ inline unsigned short f2bf(float x) {          // RNE f32 -> bf16 bits
    unsigned int u = __float_as_uint(x);
    unsigned int r = (u + 0x7fffu + ((u >> 16) & 1u)) >> 16;
    return (unsigned short)r;
}
__device__ inline float bf2f(unsigned short s) {
    return __uint_as_float(((unsigned int)s) << 16);
}
__device__ inline void split2(float x, unsigned short& h, unsigned short& l) {
    h = f2bf(x);
    l = f2bf(x - bf2f(h));
}
__device__ inline int swz(int row) { return (((row & 7) ^ ((row >> 3) & 7)) << 4); }

__device__ inline void gl2lds16(const void* g, void* l) {
    __builtin_amdgcn_global_load_lds((__attribute__((address_space(1))) const void*)g,
                                     (__attribute__((address_space(3))) void*)l, 16, 0, 0);
}

// ---------------------------------------------------------------------------
// Pre-pass 1: split fp32 -> (hi, lo) bf16 planes. grid (EL/2048, 3)
// ---------------------------------------------------------------------------
struct SplitArgs { const float* src[3]; ushortT* dh[3]; ushortT* dl[3]; };
__global__ __launch_bounds__(256) void split_plain(SplitArgs a)
{
    const int z = blockIdx.y;
    const size_t i = ((size_t)blockIdx.x * 256 + threadIdx.x) * 8;
    const float* s = a.src[z];
    float4 v0 = *reinterpret_cast<const float4*>(s + i);
    float4 v1 = *reinterpret_cast<const float4*>(s + i + 4);
    float f[8] = {v0.x, v0.y, v0.z, v0.w, v1.x, v1.y, v1.z, v1.w};
    U8 h, l;
    #pragma unroll
    for (int j = 0; j < 8; ++j) split2(f[j], h.u[j], l.u[j]);
    *reinterpret_cast<short8*>(a.dh[z] + i) = h.v;
    *reinterpret_cast<short8*>(a.dl[z] + i) = l.v;
}

// ---------------------------------------------------------------------------
// Pre-pass 2: weights -> transposed split planes Wt[n][k], x scale. grid (3,96,4)
// ---------------------------------------------------------------------------
struct WArgs { const float* src[4]; ushortT* dh[4]; ushortT* dl[4]; float scale[4]; };
__global__ __launch_bounds__(256) void split_wt(WArgs a)
{
    const int n  = blockIdx.x * 256 + threadIdx.x;   // 0..767
    const int k0 = blockIdx.y * 8;
    const int z  = blockIdx.z;
    const float* W = a.src[z];
    const float sc = a.scale[z];
    U8 h, l;
    #pragma unroll
    for (int j = 0; j < 8; ++j) {
        float x = W[(size_t)(k0 + j) * DD + n] * sc;  // coalesced across lanes
        split2(x, h.u[j], l.u[j]);
    }
    *reinterpret_cast<short8*>(a.dh[z] + (size_t)n * DD + k0) = h.v;
    *reinterpret_cast<short8*>(a.dl[z] + (size_t)n * DD + k0) = l.v;
}

// ---------------------------------------------------------------------------
// Fused QKV bf16x3 MFMA GEMM: for z in {q,k,v}: C_z = X_z @ Wt_z^T + bias_z.
// Grid (36, 64): blockIdx.x -> (z = x/12, n0 = (x%12)*64). Body = gemm_mfma<1>.
// ---------------------------------------------------------------------------
struct QkvArgs {
    const ushortT* A[3];      // qh, kh, vh (lo plane at +apb bytes)
    const ushortT* Bt[3];     // wqh, wkh, wvh (lo at +bpb bytes)
    const float* bias[3];
    float bscale[3];
    ushortT* oH[3];
    ushortT* oL[3];
};
__global__ __launch_bounds__(256) void qkv_gemm(QkvArgs qa, size_t apb, size_t bpb)
{
    __shared__ ushortT As[64 * 64];   // 8 KB, [row][hi 32 | lo 32], chunk ^= row&7
    __shared__ ushortT Bs[64 * 64];

    const int tid  = threadIdx.x;
    const int lane = tid & 63;
    const int w    = tid >> 6;
    const int g    = lane >> 4, c = lane & 15;
    const int nb   = blockIdx.x;          // 0..35
    const int z    = nb / 12;
    const int n0   = (nb % 12) * 64;
    const int m0   = blockIdx.y * 64;

    const ushortT* Ah  = qa.A[z];
    const ushortT* Bth = qa.Bt[z];

    const int srow0 = w * 16 + (lane >> 3);
    const int csrc  = (lane & 7) ^ (lane >> 3);
    const size_t plA = (csrc >= 4) ? apb : 0;
    const size_t plB = (csrc >= 4) ? bpb : 0;
    const size_t abase = (size_t)(m0 + srow0) * (DD * 2) + plA + (size_t)(csrc & 3) * 16;
    const size_t bbase = (size_t)(n0 + srow0) * (DD * 2) + plB + (size_t)(csrc & 3) * 16;

    f32x4 acc[4] = {{0,0,0,0},{0,0,0,0},{0,0,0,0},{0,0,0,0}};

    const int arow = w * 16 + c;
    const int ahc  = g ^ (arow & 7);
    const int aoff_h = arow * 64 + ahc * 8;
    const int aoff_l = arow * 64 + (ahc ^ 4) * 8;

    for (int kt = 0; kt < DD / 32; ++kt) {
        const size_t ko = (size_t)kt * 64;
        const char* asrc = (const char*)Ah  + abase + ko;
        const char* bsrc = (const char*)Bth + bbase + ko;
        gl2lds16(asrc,                &As[w * 1024]);
        gl2lds16(asrc + 8 * (DD * 2), &As[w * 1024 + 512]);
        gl2lds16(bsrc,                &Bs[w * 1024]);
        gl2lds16(bsrc + 8 * (DD * 2), &Bs[w * 1024 + 512]);
        __syncthreads();

        const short8 a_h = *reinterpret_cast<const short8*>(&As[aoff_h]);
        const short8 a_l = *reinterpret_cast<const short8*>(&As[aoff_l]);
        #pragma unroll
        for (int nf = 0; nf < 4; ++nf) {
            const int brow = nf * 16 + c;
            const int bhc  = g ^ (brow & 7);
            const short8 b_h = *reinterpret_cast<const short8*>(&Bs[brow * 64 + bhc * 8]);
            const short8 b_l = *reinterpret_cast<const short8*>(&Bs[brow * 64 + (bhc ^ 4) * 8]);
            acc[nf] = MFMA(a_h, b_h, acc[nf]);
            acc[nf] = MFMA(a_l, b_h, acc[nf]);
            acc[nf] = MFMA(a_h, b_l, acc[nf]);
        }
        __syncthreads();
    }

    ushortT* oH = qa.oH[z];
    ushortT* oL = qa.oL[z];
    const float bsc = qa.bscale[z];
    #pragma unroll
    for (int nf = 0; nf < 4; ++nf) {
        const int n = n0 + nf * 16 + c;
        const float bz = qa.bias[z][n] * bsc;
        #pragma unroll
        for (int r = 0; r < 4; ++r) {
            const int m = m0 + w * 16 + 4 * g + r;
            unsigned short hh, ll;
            split2(acc[nf][r] + bz, hh, ll);
            oH[(size_t)m * DD + n] = hh;
            oL[(size_t)m * DD + n] = ll;
        }
    }
}

// ---------------------------------------------------------------------------
// Out-projection bf16x3 MFMA GEMM (fp32 out) — unchanged R6 body.
// ---------------------------------------------------------------------------
__global__ __launch_bounds__(256) void gemm_out(const ushortT* __restrict__ Ah, size_t apb,
                                                const ushortT* __restrict__ Bth, size_t bpb,
                                                const float* __restrict__ bias,
                                                float* __restrict__ outF)
{
    __shared__ ushortT As[64 * 64];
    __shared__ ushortT Bs[64 * 64];

    const int tid  = threadIdx.x;
    const int lane = tid & 63;
    const int w    = tid >> 6;
    const int g    = lane >> 4, c = lane & 15;
    const int n0   = blockIdx.x * 64;
    const int m0   = blockIdx.y * 64;

    const int srow0 = w * 16 + (lane >> 3);
    const int csrc  = (lane & 7) ^ (lane >> 3);
    const size_t plA = (csrc >= 4) ? apb : 0;
    const size_t plB = (csrc >= 4) ? bpb : 0;
    const size_t abase = (size_t)(m0 + srow0) * (DD * 2) + plA + (size_t)(csrc & 3) * 16;
    const size_t bbase = (size_t)(n0 + srow0) * (DD * 2) + plB + (size_t)(csrc & 3) * 16;

    f32x4 acc[4] = {{0,0,0,0},{0,0,0,0},{0,0,0,0},{0,0,0,0}};

    const int arow = w * 16 + c;
    const int ahc  = g ^ (arow & 7);
    const int aoff_h = arow * 64 + ahc * 8;
    const int aoff_l = arow * 64 + (ahc ^ 4) * 8;

    for (int kt = 0; kt < DD / 32; ++kt) {
        const size_t ko = (size_t)kt * 64;
        const char* asrc = (const char*)Ah  + abase + ko;
        const char* bsrc = (const char*)Bth + bbase + ko;
        gl2lds16(asrc,                &As[w * 1024]);
        gl2lds16(asrc + 8 * (DD * 2), &As[w * 1024 + 512]);
        gl2lds16(bsrc,                &Bs[w * 1024]);
        gl2lds16(bsrc + 8 * (DD * 2), &Bs[w * 1024 + 512]);
        __syncthreads();

        const short8 a_h = *reinterpret_cast<const short8*>(&As[aoff_h]);
        const short8 a_l = *reinterpret_cast<const short8*>(&As[aoff_l]);
        #pragma unroll
        for (int nf = 0; nf < 4; ++nf) {
            const int brow = nf * 16 + c;
            const int bhc  = g ^ (brow & 7);
            const short8 b_h = *reinterpret_cast<const short8*>(&Bs[brow * 64 + bhc * 8]);
            const short8 b_l = *reinterpret_cast<const short8*>(&Bs[brow * 64 + (bhc ^ 4) * 8]);
            acc[nf] = MFMA(a_h, b_h, acc[nf]);
            acc[nf] = MFMA(a_l, b_h, acc[nf]);
            acc[nf] = MFMA(a_h, b_l, acc[nf]);
        }
        __syncthreads();
    }

    #pragma unroll
    for (int nf = 0; nf < 4; ++nf) {
        const int n = n0 + nf * 16 + c;
        const float bz = bias[n];
        #pragma unroll
        for (int r = 0; r < 4; ++r) {
            const int m = m0 + w * 16 + 4 * g + r;
            outF[(size_t)m * DD + n] = acc[nf][r] + bz;
        }
    }
}

// ---------------------------------------------------------------------------
// Flash attention, swapped-QK^T 32x32, bf16x3, in-register softmax,
// double-buffered async staging (T14), XCD-grouped block remap.
// Grid: 768 1D. Decode: xcd = wg&7, slot = wg>>3, bh = xcd*3 + slot/32,
// qblk = slot%32 — all q-blocks of one bh land on one XCD (K/V L2-resident).
// Block: 128 thr = 2 waves; wave owns 32 q-rows.
// ---------------------------------------------------------------------------
__global__ __launch_bounds__(128) void attn_mfma(const ushortT* __restrict__ Qh_g,
                                                 const ushortT* __restrict__ Ql_g,
                                                 const ushortT* __restrict__ Kh_g,
                                                 const ushortT* __restrict__ Kl_g,
                                                 const ushortT* __restrict__ Vh_g,
                                                 const ushortT* __restrict__ Vl_g,
                                                 const float* __restrict__ mask,
                                                 ushortT* __restrict__ Oh_g,
                                                 ushortT* __restrict__ Ol_g)
{
    __shared__ ushortT KhS[2][32 * 64];   // [key][d], chunk ^= key&7
    __shared__ ushortT KlS[2][32 * 64];
    __shared__ ushortT VtS[2][64 * 64];   // [d][key hi 32 | key lo 32], swz(d)
    __shared__ float mterm[LL];           // 8 KB, whole mask row for this b

    const int tid  = threadIdx.x;
    const int lane = tid & 63;
    const int w    = tid >> 6;        // 2 waves
    const int qc   = lane & 31;       // q column
    const int h5   = lane >> 5;

    const int wg   = blockIdx.x;      // 0..767
    const int xcd  = wg & 7;
    const int slot = wg >> 3;         // 0..95
    const int bh   = xcd * 3 + (slot >> 5);
    const int qblk = slot & 31;
    const int b    = bh / NH;
    const int h    = bh % NH;
    const int qrow = qblk * 64 + w * 32 + qc;

    // ---- preload mask row -> mterm (once per block) ----
    {
        const float* mrow = mask + (size_t)b * LL;
        #pragma unroll
        for (int t = 0; t < 16; ++t) {
            const int i = tid + 128 * t;
            mterm[i] = (1.0f - mrow[i]) * -99999.0f;
        }
    }

    // ---- Q B-frags: col q = qc, k d = 8*h5 + j + 16*ks (pre-scaled by 1/8)
    short8 qbh[4], qbl[4];
    {
        const size_t qoff = (size_t)(b * LL + qrow) * DD + h * 64;
        #pragma unroll
        for (int ks = 0; ks < 4; ++ks) {
            const int d0 = 8 * h5 + 16 * ks;
            qbh[ks] = *reinterpret_cast<const short8*>(Qh_g + qoff + d0);
            qbl[ks] = *reinterpret_cast<const short8*>(Ql_g + qoff + d0);
        }
    }

    f32x16 Oa[2];
    #pragma unroll
    for (int m = 0; m < 2; ++m)
        #pragma unroll
        for (int r = 0; r < 16; ++r) Oa[m][r] = 0.f;
    float mrun = -1e30f, lrun = 0.f;

    // staging geometry
    const int skey   = tid >> 2;              // V: key 0..31
    const int sd0v   = (tid & 3) * 16;        // V: 16 d per thread
    const int krow_l = lane >> 3;             // K: row within 8-row issue
    const int kcsrc  = (lane & 7) ^ krow_l;   // inverse-swizzled source chunk
    const ushortT* ksrcp = w ? Kl_g : Kh_g;   // wave0 -> Kh, wave1 -> Kl
    const size_t kbase0 = (size_t)(b * LL + krow_l) * DD + h * 64 + kcsrc * 8;
    const size_t vbase0 = (size_t)(b * LL + skey) * DD + h * 64 + sd0v;

    U8 vr0, vr1, vr2, vr3;   // V in-flight registers (issue-early / write-late)

    auto KSTAGE = [&](int bufi, int kt) {
        ushortT* kd = w ? KlS[bufi] : KhS[bufi];
        const ushortT* ks_ = ksrcp + kbase0 + (size_t)(kt * 32) * DD;
        #pragma unroll
        for (int t = 0; t < 4; ++t)
            gl2lds16(ks_ + (size_t)(8 * t) * DD, kd + t * 512);
    };
    auto VLOAD = [&](int kt) {
        const ushortT* vh_ = Vh_g + vbase0 + (size_t)(kt * 32) * DD;
        const ushortT* vl_ = Vl_g + vbase0 + (size_t)(kt * 32) * DD;
        vr0.v = *reinterpret_cast<const short8*>(vh_);
        vr1.v = *reinterpret_cast<const short8*>(vh_ + 8);
        vr2.v = *reinterpret_cast<const short8*>(vl_);
        vr3.v = *reinterpret_cast<const short8*>(vl_ + 8);
    };
    auto VWRITE = [&](int bufi) {
        ushortT* vt = VtS[bufi];
        #pragma unroll
        for (int j = 0; j < 8; ++j) {
            int d = sd0v + j; int s = swz(d);
            vt[d * 64 + (((2 * skey) ^ s) >> 1)]      = vr0.u[j];
            vt[d * 64 + (((64 + 2 * skey) ^ s) >> 1)] = vr2.u[j];
            d = sd0v + 8 + j; s = swz(d);
            vt[d * 64 + (((2 * skey) ^ s) >> 1)]      = vr1.u[j];
            vt[d * 64 + (((64 + 2 * skey) ^ s) >> 1)] = vr3.u[j];
        }
    };

    // prologue: stage tile 0 into buffer 0
    VLOAD(0);
    KSTAGE(0, 0);
    VWRITE(0);

    for (int kt = 0; kt < NT; ++kt) {
        const int cur = kt & 1;
        __syncthreads();                  // buf[cur] staged; buf[cur^1] free
        const bool pf = (kt + 1 < NT);
        if (pf) {                          // issue next tile's loads early
            KSTAGE(cur ^ 1, kt + 1);
            VLOAD(kt + 1);
        }

        // ---- S^T = K . Q^T  (bf16x3; two independent 6-MFMA chains) ----
        const ushortT* KhC = KhS[cur];
        const ushortT* KlC = KlS[cur];
        f32x16 sa0, sa1;
        #pragma unroll
        for (int r = 0; r < 16; ++r) { sa0[r] = 0.f; sa1[r] = 0.f; }
        #pragma unroll
        for (int ks = 0; ks < 2; ++ks) {
            const int ch = (h5 + 2 * ks) ^ (qc & 7);
            const short8 kfh = *reinterpret_cast<const short8*>(&KhC[qc * 64 + ch * 8]);
            const short8 kfl = *reinterpret_cast<const short8*>(&KlC[qc * 64 + ch * 8]);
            sa0 = MFMA32(kfh, qbh[ks], sa0);
            sa0 = MFMA32(kfl, qbh[ks], sa0);
            sa0 = MFMA32(kfh, qbl[ks], sa0);
        }
        #pragma unroll
        for (int ks = 2; ks < 4; ++ks) {
            const int ch = (h5 + 2 * ks) ^ (qc & 7);
            const short8 kfh = *reinterpret_cast<const short8*>(&KhC[qc * 64 + ch * 8]);
            const short8 kfl = *reinterpret_cast<const short8*>(&KlC[qc * 64 + ch * 8]);
            sa1 = MFMA32(kfh, qbh[ks], sa1);
            sa1 = MFMA32(kfl, qbh[ks], sa1);
            sa1 = MFMA32(kfh, qbl[ks], sa1);
        }

        // ---- in-register online softmax (lane owns q-row qc) ----
        float sm[16];
        #pragma unroll
        for (int r = 0; r < 16; ++r)
            sm[r] = sa0[r] + sa1[r] + mterm[kt * 32 + (r & 3) + 8 * (r >> 2) + 4 * h5];
        float tm = sm[0];
        #pragma unroll
        for (int r = 1; r < 16; ++r) tm = fmaxf(tm, sm[r]);
        tm = fmaxf(tm, __shfl_xor(tm, 32));
        const float mn = fmaxf(mrun, tm);
        const float scale = __expf(mrun - mn);
        float p[16];
        float rs = 0.f;
        #pragma unroll
        for (int r = 0; r < 16; ++r) { p[r] = __expf(sm[r] - mn); rs += p[r]; }
        rs += __shfl_xor(rs, 32);
        lrun = lrun * scale + rs;
        mrun = mn;
        #pragma unroll
        for (int m = 0; m < 2; ++m)
            #pragma unroll
            for (int r = 0; r < 16; ++r) Oa[m][r] *= scale;

        // ---- P -> bf16 packs + cross-half exchange (registers only) ----
        unsigned int pkh[8], pkl[8], xph[8], xpl[8];
        #pragma unroll
        for (int s2 = 0; s2 < 8; ++s2) {
            unsigned short h0, l0, h1, l1;
            split2(p[2 * s2],     h0, l0);
            split2(p[2 * s2 + 1], h1, l1);
            pkh[s2] = (unsigned int)h0 | ((unsigned int)h1 << 16);
            pkl[s2] = (unsigned int)l0 | ((unsigned int)l1 << 16);
            xph[s2] = __shfl_xor(pkh[s2], 32);
            xpl[s2] = __shfl_xor(pkl[s2], 32);
        }
        UB pbh[2], pbl[2];
        if (h5 == 0) {
            pbh[0].u = (u32x4){pkh[0], pkh[1], xph[0], xph[1]};
            pbl[0].u = (u32x4){pkl[0], pkl[1], xpl[0], xpl[1]};
            pbh[1].u = (u32x4){pkh[4], pkh[5], xph[4], xph[5]};
            pbl[1].u = (u32x4){pkl[4], pkl[5], xpl[4], xpl[5]};
        } else {
            pbh[0].u = (u32x4){xph[2], xph[3], pkh[2], pkh[3]};
            pbl[0].u = (u32x4){xpl[2], xpl[3], pkl[2], pkl[3]};
            pbh[1].u = (u32x4){xph[6], xph[7], pkh[6], pkh[7]};
            pbl[1].u = (u32x4){xpl[6], xpl[7], pkl[6], pkl[7]};
        }

        // ---- O^T += V^T . P^T ----
        const ushortT* VtC = VtS[cur];
        #pragma unroll
        for (int m = 0; m < 2; ++m) {
            const int d  = qc + 32 * m;
            const int sv = swz(d);
            #pragma unroll
            for (int ks2 = 0; ks2 < 2; ++ks2) {
                const int bc = 16 * h5 + 32 * ks2;
                const short8 vfh = *reinterpret_cast<const short8*>(&VtC[d * 64 + ((bc ^ sv) >> 1)]);
                const short8 vfl = *reinterpret_cast<const short8*>(&VtC[d * 64 + (((64 + bc) ^ sv) >> 1)]);
                Oa[m] = MFMA32(vfh, pbh[ks2].v, Oa[m]);
                Oa[m] = MFMA32(vfl, pbh[ks2].v, Oa[m]);
                Oa[m] = MFMA32(vfh, pbl[ks2].v, Oa[m]);
            }
        }

        if (pf) VWRITE(cur ^ 1);   // write-late: HBM latency hid under compute
    }

    // ---- epilogue: O^T / l, split-store bf16 hi/lo ----
    const float inv = 1.0f / lrun;
    const size_t obase = (size_t)(b * LL + qrow) * DD + h * 64;
    #pragma unroll
    for (int m = 0; m < 2; ++m)
        #pragma unroll
        for (int r = 0; r < 16; ++r) {
            const int d = (r & 3) + 8 * (r >> 2) + 4 * h5 + 32 * m;
            unsigned short hh, ll;
            split2(Oa[m][r] * inv, hh, ll);
            Oh_g[obase + d] = hh;
            Ol_g[obase + d] = ll;
        }
}

// ---------------------------------------------------------------------------
extern "C" void kernel_launch(void* const* d_in, const int* in_sizes, int n_in,
                              void* d_out, int out_size, void* d_ws, size_t ws_size,
                              hipStream_t stream)
{
    const float* q    = (const float*)d_in[0];
    const float* k    = (const float*)d_in[1];
    const float* v    = (const float*)d_in[2];
    const float* amask= (const float*)d_in[3];
    const float* Wq   = (const float*)d_in[4];
    const float* bq   = (const float*)d_in[5];
    const float* Wk   = (const float*)d_in[6];
    const float* bk   = (const float*)d_in[7];
    const float* Wv   = (const float*)d_in[8];
    const float* bv   = (const float*)d_in[9];
    const float* Wo   = (const float*)d_in[10];
    const float* bo   = (const float*)d_in[11];
    float* out = (float*)d_out;

    // ws map (ushort units): 6 input planes | 8 weight planes | 6 proj planes
    ushortT* W0 = (ushortT*)d_ws;
    ushortT* qh = W0;                 ushortT* ql = W0 + (size_t)EL;
    ushortT* kh = W0 + 2*(size_t)EL;  ushortT* kl = W0 + 3*(size_t)EL;
    ushortT* vh = W0 + 4*(size_t)EL;  ushortT* vl = W0 + 5*(size_t)EL;
    ushortT* wb = W0 + 6*(size_t)EL;
    ushortT* wqh = wb;                 ushortT* wql = wb + (size_t)WEL;
    ushortT* wkh = wb + 2*(size_t)WEL; ushortT* wkl = wb + 3*(size_t)WEL;
    ushortT* wvh = wb + 4*(size_t)WEL; ushortT* wvl = wb + 5*(size_t)WEL;
    ushortT* woh = wb + 6*(size_t)WEL; ushortT* wol = wb + 7*(size_t)WEL;
    ushortT* pb = wb + 8*(size_t)WEL;
    ushortT* Qph = pb;                 ushortT* Qpl = pb + (size_t)EL;
    ushortT* Kph = pb + 2*(size_t)EL;  ushortT* Kpl = pb + 3*(size_t)EL;
    ushortT* Vph = pb + 4*(size_t)EL;  ushortT* Vpl = pb + 5*(size_t)EL;
    ushortT* Oh = W0;                  ushortT* Ol = W0 + (size_t)EL;   // alias q/k

    const size_t APB = (size_t)EL * 2;    // activation hi->lo plane gap, bytes
    const size_t WPB = (size_t)WEL * 2;   // weight hi->lo plane gap, bytes

    SplitArgs sa;
    sa.src[0] = q; sa.src[1] = k; sa.src[2] = v;
    sa.dh[0] = qh; sa.dh[1] = kh; sa.dh[2] = vh;
    sa.dl[0] = ql; sa.dl[1] = kl; sa.dl[2] = vl;
    split_plain<<<dim3(EL / 2048, 3), 256, 0, stream>>>(sa);

    WArgs wa;
    wa.src[0] = Wq; wa.src[1] = Wk; wa.src[2] = Wv; wa.src[3] = Wo;
    wa.dh[0] = wqh; wa.dh[1] = wkh; wa.dh[2] = wvh; wa.dh[3] = woh;
    wa.dl[0] = wql; wa.dl[1] = wkl; wa.dl[2] = wvl; wa.dl[3] = wol;
    wa.scale[0] = 0.125f; wa.scale[1] = 1.f; wa.scale[2] = 1.f; wa.scale[3] = 1.f;
    split_wt<<<dim3(3, 96, 4), 256, 0, stream>>>(wa);

    // fused QKV projections (split bf16 out), 2304 blocks
    QkvArgs qa;
    qa.A[0] = qh;  qa.A[1] = kh;  qa.A[2] = vh;
    qa.Bt[0] = wqh; qa.Bt[1] = wkh; qa.Bt[2] = wvh;
    qa.bias[0] = bq; qa.bias[1] = bk; qa.bias[2] = bv;
    qa.bscale[0] = 0.125f; qa.bscale[1] = 1.f; qa.bscale[2] = 1.f;
    qa.oH[0] = Qph; qa.oH[1] = Kph; qa.oH[2] = Vph;
    qa.oL[0] = Qpl; qa.oL[1] = Kpl; qa.oL[2] = Vpl;
    qkv_gemm<<<dim3(36, 64), 256, 0, stream>>>(qa, APB, WPB);

    // attention (1D grid, XCD-grouped remap inside)
    attn_mfma<<<dim3(768), 128, 0, stream>>>(Qph, Qpl, Kph, Kpl, Vph, Vpl, amask, Oh, Ol);

    // output projection (fp32 out)
    gemm_out<<<dim3(DD / 64, 4096 / 64), 256, 0, stream>>>(Oh, APB, woh, WPB, bo, out);
}